// Round 6
// baseline (13210.535 us; speedup 1.0000x reference)
//
#include <hip/hip_runtime.h>
#include <math.h>

#define SQ 8
#define NN 100000
#define EE 1600000
#define LL 3
#define BB 128
#define HRR 128
#define TILE 64                        // nodes per block (4 waves x 16 nodes)
#define NTILE ((NN + TILE - 1) / TILE) // 1563 blocks (round-4 cache-friendly grid)
#define NBLK ((NN + 255) / 256)        // 391 (scan kernels)

__device__ __forceinline__ float fast_tanh(float x) {
    x = fminf(fmaxf(x, -15.f), 15.f);
    float e = __expf(2.f * x);
    return (e - 1.f) * __builtin_amdgcn_rcpf(e + 1.f);
}

// ---------------- CSR build ----------------

__global__ void k_hist(const int* __restrict__ dst, int* __restrict__ deg) {
    int e = blockIdx.x * blockDim.x + threadIdx.x;
    if (e < EE) atomicAdd(&deg[dst[e]], 1);
}

__global__ void k_scan1(const int* __restrict__ deg, int* __restrict__ excl,
                        int* __restrict__ bsums) {
    __shared__ int buf[256];
    int tid = threadIdx.x;
    int i = blockIdx.x * 256 + tid;
    int v = (i < NN) ? deg[i] : 0;
    buf[tid] = v;
    __syncthreads();
    for (int off = 1; off < 256; off <<= 1) {
        int t = (tid >= off) ? buf[tid - off] : 0;
        __syncthreads();
        buf[tid] += t;
        __syncthreads();
    }
    if (i < NN) excl[i] = buf[tid] - v;
    if (tid == 255) bsums[blockIdx.x] = buf[255];
}

__global__ void k_scan2(const int* __restrict__ bsums, int* __restrict__ boff) {
    __shared__ int buf[512];
    int tid = threadIdx.x;
    int v = (tid < NBLK) ? bsums[tid] : 0;
    buf[tid] = v;
    __syncthreads();
    for (int off = 1; off < 512; off <<= 1) {
        int t = (tid >= off) ? buf[tid - off] : 0;
        __syncthreads();
        buf[tid] += t;
        __syncthreads();
    }
    if (tid < NBLK) boff[tid] = buf[tid] - v;
}

__global__ void k_scan3(int* __restrict__ row_start, const int* __restrict__ boff,
                        int* __restrict__ cursor) {
    int tid = threadIdx.x;
    int i = blockIdx.x * 256 + tid;
    if (i < NN) {
        int r = row_start[i] + boff[blockIdx.x];
        row_start[i] = r;
        cursor[i] = r;
    }
    if (blockIdx.x == 0 && tid == 0) row_start[NN] = EE;
}

__global__ void k_fill(const int* __restrict__ src, const int* __restrict__ dst,
                       int* __restrict__ cursor, int* __restrict__ csr) {
    int e = blockIdx.x * blockDim.x + threadIdx.x;
    if (e < EE) {
        int d = dst[e];
        int p = atomicAdd(&cursor[d], 1);
        csr[p] = src[e];
    }
}

// ---------------- GIN stage 1: agg + MLP1 + BN partial stats ----------------
// wave = 4 node-groups of 16 lanes; each lane holds 4 channels (float4).
// One gather instruction fetches 4 rows (1 KiB) -> 4x MLP vs round-4.

__global__ __launch_bounds__(256, 6) void k_agg_mlp1(
    const float* __restrict__ xin, const int* __restrict__ row_start,
    const int* __restrict__ csr, const float* __restrict__ W1,
    const float* __restrict__ b1, float* __restrict__ h_out,
    float* __restrict__ stats) {
    __shared__ float sW[4096];
    __shared__ float4 sS[4][16];
    __shared__ float4 sQ[4][16];
    int tid = threadIdx.x;
    for (int k = tid; k < 4096; k += 256) sW[k] = W1[k];
    __syncthreads();
    int wave = tid >> 6, lane = tid & 63;
    int sub = lane & 15;      // sublane within group (channel quad index)
    int gbase = lane & 48;    // group * 16
    float4 b4 = *(const float4*)&b1[sub * 4];
    float4 aS = {0.f, 0.f, 0.f, 0.f}, aQ = {0.f, 0.f, 0.f, 0.f};
    int nbase = blockIdx.x * TILE + wave * 16;
    for (int r = 0; r < 4; r++) {
        int i = nbase + r * 4 + (gbase >> 4);   // this group's node
        bool valid = (i < NN);
        int e0 = 0, e1 = 0;
        float4 s0 = {0.f, 0.f, 0.f, 0.f}, s1 = {0.f, 0.f, 0.f, 0.f};
        if (valid) {
            e0 = row_start[i];
            e1 = row_start[i + 1];
            s0 = *(const float4*)&xin[(size_t)i * 64 + sub * 4];
        }
        for (int eb = e0; __any(eb < e1); eb += 16) {
            int e = eb + sub;
            int id = (e < e1) ? csr[e] : 0;
#pragma unroll
            for (int k = 0; k < 16; k += 2) {
                int nb0 = __shfl(id, gbase + k, 64);
                int nb1 = __shfl(id, gbase + k + 1, 64);
                bool v0 = (eb + k) < e1;        // uniform within group
                bool v1 = (eb + k + 1) < e1;
                float4 t0 = *(const float4*)&xin[(size_t)(v0 ? nb0 : 0) * 64 + sub * 4];
                float4 t1 = *(const float4*)&xin[(size_t)(v1 ? nb1 : 0) * 64 + sub * 4];
                if (v0) { s0.x += t0.x; s0.y += t0.y; s0.z += t0.z; s0.w += t0.w; }
                if (v1) { s1.x += t1.x; s1.y += t1.y; s1.z += t1.z; s1.w += t1.w; }
            }
        }
        float4 s;
        s.x = s0.x + s1.x; s.y = s0.y + s1.y; s.z = s0.z + s1.z; s.w = s0.w + s1.w;
        // MLP1: h[out] = b + sum_c s[c] * W[c][out], packed float4 over 16 lanes
        float4 h0 = b4, h1 = {0.f, 0.f, 0.f, 0.f};
#pragma unroll
        for (int c = 0; c < 64; c += 4) {
            int srcl = gbase + (c >> 2);
            float scx = __shfl(s.x, srcl, 64);
            float scy = __shfl(s.y, srcl, 64);
            float scz = __shfl(s.z, srcl, 64);
            float scw = __shfl(s.w, srcl, 64);
            float4 w0 = *(const float4*)&sW[(c + 0) * 64 + sub * 4];
            float4 w1 = *(const float4*)&sW[(c + 1) * 64 + sub * 4];
            float4 w2 = *(const float4*)&sW[(c + 2) * 64 + sub * 4];
            float4 w3 = *(const float4*)&sW[(c + 3) * 64 + sub * 4];
            h0.x = fmaf(scx, w0.x, h0.x); h0.y = fmaf(scx, w0.y, h0.y);
            h0.z = fmaf(scx, w0.z, h0.z); h0.w = fmaf(scx, w0.w, h0.w);
            h1.x = fmaf(scy, w1.x, h1.x); h1.y = fmaf(scy, w1.y, h1.y);
            h1.z = fmaf(scy, w1.z, h1.z); h1.w = fmaf(scy, w1.w, h1.w);
            h0.x = fmaf(scz, w2.x, h0.x); h0.y = fmaf(scz, w2.y, h0.y);
            h0.z = fmaf(scz, w2.z, h0.z); h0.w = fmaf(scz, w2.w, h0.w);
            h1.x = fmaf(scw, w3.x, h1.x); h1.y = fmaf(scw, w3.y, h1.y);
            h1.z = fmaf(scw, w3.z, h1.z); h1.w = fmaf(scw, w3.w, h1.w);
        }
        float4 h;
        h.x = h0.x + h1.x; h.y = h0.y + h1.y; h.z = h0.z + h1.z; h.w = h0.w + h1.w;
        if (valid) {
            *(float4*)&h_out[(size_t)i * 64 + sub * 4] = h;
            aS.x += h.x; aS.y += h.y; aS.z += h.z; aS.w += h.w;
            aQ.x += h.x * h.x; aQ.y += h.y * h.y; aQ.z += h.z * h.z; aQ.w += h.w * h.w;
        }
    }
    // reduce across the 4 groups (lane bits 4,5)
    aS.x += __shfl_xor(aS.x, 16, 64); aS.y += __shfl_xor(aS.y, 16, 64);
    aS.z += __shfl_xor(aS.z, 16, 64); aS.w += __shfl_xor(aS.w, 16, 64);
    aS.x += __shfl_xor(aS.x, 32, 64); aS.y += __shfl_xor(aS.y, 32, 64);
    aS.z += __shfl_xor(aS.z, 32, 64); aS.w += __shfl_xor(aS.w, 32, 64);
    aQ.x += __shfl_xor(aQ.x, 16, 64); aQ.y += __shfl_xor(aQ.y, 16, 64);
    aQ.z += __shfl_xor(aQ.z, 16, 64); aQ.w += __shfl_xor(aQ.w, 16, 64);
    aQ.x += __shfl_xor(aQ.x, 32, 64); aQ.y += __shfl_xor(aQ.y, 32, 64);
    aQ.z += __shfl_xor(aQ.z, 32, 64); aQ.w += __shfl_xor(aQ.w, 32, 64);
    if (lane < 16) { sS[wave][sub] = aS; sQ[wave][sub] = aQ; }
    __syncthreads();
    if (tid < 16) {
        float4 s = sS[0][tid], q = sQ[0][tid];
        for (int w = 1; w < 4; w++) {
            float4 a = sS[w][tid], b = sQ[w][tid];
            s.x += a.x; s.y += a.y; s.z += a.z; s.w += a.w;
            q.x += b.x; q.y += b.y; q.z += b.z; q.w += b.w;
        }
        atomicAdd(&stats[tid * 4 + 0], s.x);
        atomicAdd(&stats[tid * 4 + 1], s.y);
        atomicAdd(&stats[tid * 4 + 2], s.z);
        atomicAdd(&stats[tid * 4 + 3], s.w);
        atomicAdd(&stats[64 + tid * 4 + 0], q.x);
        atomicAdd(&stats[64 + tid * 4 + 1], q.y);
        atomicAdd(&stats[64 + tid * 4 + 2], q.z);
        atomicAdd(&stats[64 + tid * 4 + 3], q.w);
    }
}

// ---------------- GIN stage 2: BN + tanh + MLP2 + tanh (+ pool) — round-4 form ----------------

__global__ __launch_bounds__(256, 6) void k_bn_mlp2(
    const float* __restrict__ h_in, const float* __restrict__ W2,
    const float* __restrict__ b2, const float* __restrict__ gamma,
    const float* __restrict__ beta, const float* __restrict__ stats,
    float* __restrict__ x_out, float* __restrict__ g_pool,
    const int* __restrict__ batch) {
    __shared__ float sW[4096];
    int tid = threadIdx.x;
    for (int k = tid; k < 4096; k += 256) sW[k] = W2[k];
    __syncthreads();
    int wave = tid >> 6, lane = tid & 63;
    float bias = b2[lane];
    float mu = stats[lane] * (1.0f / NN);
    float var = stats[64 + lane] * (1.0f / NN) - mu * mu;
    float scale = rsqrtf(var + 1e-5f) * gamma[lane];
    float shift = beta[lane] - mu * scale;
    int base = blockIdx.x * TILE + wave * 16;
    float pacc = 0.f;
    int pbid = -1;
    for (int r = 0; r < 16; r++) {
        int i = base + r;
        if (i >= NN) break;
        float v = h_in[(size_t)i * 64 + lane];
        float s = fast_tanh(fmaf(v, scale, shift));
        float h0 = bias, h1 = 0.f, h2 = 0.f, h3 = 0.f;
#pragma unroll
        for (int c = 0; c < 64; c += 4) {
            h0 = fmaf(__shfl(s, c + 0, 64), sW[(c + 0) * 64 + lane], h0);
            h1 = fmaf(__shfl(s, c + 1, 64), sW[(c + 1) * 64 + lane], h1);
            h2 = fmaf(__shfl(s, c + 2, 64), sW[(c + 2) * 64 + lane], h2);
            h3 = fmaf(__shfl(s, c + 3, 64), sW[(c + 3) * 64 + lane], h3);
        }
        float o = fast_tanh((h0 + h1) + (h2 + h3));
        if (x_out) {
            x_out[(size_t)i * 64 + lane] = o;
        } else {
            int bid = batch[i];  // sorted -> few distinct per wave
            if (bid != pbid) {
                if (pbid >= 0) atomicAdd(&g_pool[pbid * 64 + lane], pacc);
                pacc = 0.f;
                pbid = bid;
            }
            pacc += o;
        }
    }
    if (g_pool && pbid >= 0) atomicAdd(&g_pool[pbid * 64 + lane], pacc);
}

// ---------------- tail ----------------

__global__ void k_pool_proj(const float* __restrict__ g_all, const float* __restrict__ Wg,
                            const float* __restrict__ bg, float* __restrict__ seq) {
    int idx = blockIdx.x * 256 + threadIdx.x;  // S*B*64
    int o = idx & 63, row = idx >> 6;
    float acc = bg[o];
    const float* g = g_all + (size_t)row * 64;
#pragma unroll 8
    for (int c = 0; c < 64; c++) acc = fmaf(g[c], Wg[c * 64 + o], acc);
    seq[idx] = acc;
}

__global__ void k_transpose(const float* __restrict__ in, float* __restrict__ out,
                            int rows, int cols) {
    int idx = blockIdx.x * blockDim.x + threadIdx.x;
    if (idx < rows * cols) {
        int r = idx / cols, c = idx % cols;
        out[c * rows + r] = in[idx];
    }
}

// one block per batch row; loops all 8 timesteps + final sigmoid readout
__global__ __launch_bounds__(128) void k_rnn_all(
    const float* __restrict__ seq, const float* __restrict__ WihT,
    const float* __restrict__ WhhT, const float* __restrict__ bih,
    const float* __restrict__ bhh, const float* __restrict__ Wr,
    const float* __restrict__ br, float* __restrict__ out) {
    int b = blockIdx.x, j = threadIdx.x;
    __shared__ float sh[128];
    __shared__ float sx[64];
    __shared__ float sp[128];
    sh[j] = 0.f;
    float bsum = bih[j] + bhh[j];
    __syncthreads();
    for (int t = 0; t < SQ; t++) {
        if (j < 64) sx[j] = seq[((size_t)t * BB + b) * 64 + j];
        __syncthreads();
        float acc = bsum;
#pragma unroll 16
        for (int c = 0; c < 64; c++) acc = fmaf(sx[c], WihT[c * 128 + j], acc);
#pragma unroll 16
        for (int k = 0; k < 128; k++) acc = fmaf(sh[k], WhhT[k * 128 + j], acc);
        acc = tanhf(acc);
        __syncthreads();
        sh[j] = acc;
        __syncthreads();
    }
    sp[j] = sh[j] * Wr[j];
    __syncthreads();
    if (j == 0) {
        float a = br[0];
        for (int k = 0; k < 128; k++) a += sp[k];
        out[b] = 1.f / (1.f + expf(-a));
    }
}

// ---------------- launch ----------------

extern "C" void kernel_launch(void* const* d_in, const int* in_sizes, int n_in,
                              void* d_out, int out_size, void* d_ws, size_t ws_size,
                              hipStream_t stream) {
    const float* xs    = (const float*)d_in[0];
    const int*   edge  = (const int*)d_in[1];
    const int*   batch = (const int*)d_in[2];
    const float* W1    = (const float*)d_in[3];
    const float* b1    = (const float*)d_in[4];
    const float* gamma = (const float*)d_in[5];
    const float* beta  = (const float*)d_in[6];
    const float* W2    = (const float*)d_in[7];
    const float* b2    = (const float*)d_in[8];
    const float* Wg    = (const float*)d_in[9];
    const float* bg    = (const float*)d_in[10];
    const float* Wih   = (const float*)d_in[11];
    const float* Whh   = (const float*)d_in[12];
    const float* bih   = (const float*)d_in[13];
    const float* bhh   = (const float*)d_in[14];
    const float* Wr    = (const float*)d_in[15];
    const float* br    = (const float*)d_in[16];

    char* p = (char*)d_ws;
    auto alloc = [&](size_t bytes) -> char* {
        char* r = p;
        p += (bytes + 255) & ~(size_t)255;
        return r;
    };
    float* x_cur     = (float*)alloc((size_t)NN * 64 * 4);
    float* h_tmp     = (float*)alloc((size_t)NN * 64 * 4);
    float* g_all     = (float*)alloc((size_t)SQ * BB * 64 * 4);
    float* seq       = (float*)alloc((size_t)SQ * BB * 64 * 4);
    float* WihT      = (float*)alloc((size_t)64 * HRR * 4);
    float* WhhT      = (float*)alloc((size_t)HRR * HRR * 4);
    float* stats     = (float*)alloc((size_t)SQ * LL * 128 * 4);
    int*   row_start = (int*)alloc((size_t)(NN + 1) * 4);
    int*   cursor    = (int*)alloc((size_t)NN * 4);
    int*   deg       = (int*)alloc((size_t)NN * 4);
    int*   csr       = (int*)alloc((size_t)EE * 4);
    int*   bsums     = (int*)alloc(512 * 4);
    int*   boff      = (int*)alloc(512 * 4);

    hipMemsetAsync(stats, 0, (size_t)SQ * LL * 128 * 4, stream);
    hipMemsetAsync(g_all, 0, (size_t)SQ * BB * 64 * 4, stream);
    k_transpose<<<(128 * 64 + 255) / 256, 256, 0, stream>>>(Wih, WihT, 128, 64);
    k_transpose<<<(128 * 128 + 255) / 256, 256, 0, stream>>>(Whh, WhhT, 128, 128);

    int ghist = EE / 256;  // 6250
    for (int t = 0; t < SQ; t++) {
        const int* src = edge + (size_t)t * 2 * EE;
        const int* dst = src + EE;
        hipMemsetAsync(deg, 0, (size_t)NN * 4, stream);
        k_hist<<<ghist, 256, 0, stream>>>(dst, deg);
        k_scan1<<<NBLK, 256, 0, stream>>>(deg, row_start, bsums);
        k_scan2<<<1, 512, 0, stream>>>(bsums, boff);
        k_scan3<<<NBLK, 256, 0, stream>>>(row_start, boff, cursor);
        k_fill<<<ghist, 256, 0, stream>>>(src, dst, cursor, csr);
        for (int l = 0; l < LL; l++) {
            int pl = t * LL + l;
            const float* xin = (l == 0) ? xs + (size_t)t * NN * 64 : x_cur;
            k_agg_mlp1<<<NTILE, 256, 0, stream>>>(xin, row_start, csr,
                                                  W1 + (size_t)pl * 4096, b1 + (size_t)pl * 64,
                                                  h_tmp, stats + (size_t)pl * 128);
            k_bn_mlp2<<<NTILE, 256, 0, stream>>>(h_tmp, W2 + (size_t)pl * 4096,
                                                 b2 + (size_t)pl * 64, gamma + (size_t)pl * 64,
                                                 beta + (size_t)pl * 64, stats + (size_t)pl * 128,
                                                 (l < 2) ? x_cur : nullptr,
                                                 (l == 2) ? (g_all + (size_t)t * BB * 64) : nullptr,
                                                 batch);
        }
    }
    k_pool_proj<<<SQ * BB * 64 / 256, 256, 0, stream>>>(g_all, Wg, bg, seq);
    k_rnn_all<<<BB, 128, 0, stream>>>(seq, WihT, WhhT, bih, bhh, Wr, br, (float*)d_out);
}

// Round 8
// 7776.656 us; speedup vs baseline: 1.6987x; 1.6987x over previous
//
#include <hip/hip_runtime.h>
#include <math.h>

#define SQ 8
#define NN 100000
#define EE 1600000
#define LL 3
#define BB 128
#define HRR 128
#define ROWS 16                        // nodes per wave (round-4 known-good)
#define TILE 64                        // nodes per block (4 waves)
#define NTILE ((NN + TILE - 1) / TILE) // 1563 blocks
#define NBLK ((NN + 255) / 256)        // 391 (scan kernels)

__device__ __forceinline__ float fast_tanh(float x) {
    x = fminf(fmaxf(x, -15.f), 15.f);
    float e = __expf(2.f * x);
    return (e - 1.f) * __builtin_amdgcn_rcpf(e + 1.f);
}

__device__ __forceinline__ unsigned short f2bf(float f) {   // RNE fp32->bf16
    unsigned u = __float_as_uint(f);
    u = (u + 0x7FFFu + ((u >> 16) & 1u)) >> 16;
    return (unsigned short)u;
}
__device__ __forceinline__ float bf2f(unsigned short v) {
    return __uint_as_float(((unsigned)v) << 16);
}

// ---------------- CSR build ----------------

__global__ void k_hist(const int* __restrict__ dst, int* __restrict__ deg) {
    int e = blockIdx.x * blockDim.x + threadIdx.x;
    if (e < EE) atomicAdd(&deg[dst[e]], 1);
}

__global__ void k_scan1(const int* __restrict__ deg, int* __restrict__ excl,
                        int* __restrict__ bsums) {
    __shared__ int buf[256];
    int tid = threadIdx.x;
    int i = blockIdx.x * 256 + tid;
    int v = (i < NN) ? deg[i] : 0;
    buf[tid] = v;
    __syncthreads();
    for (int off = 1; off < 256; off <<= 1) {
        int t = (tid >= off) ? buf[tid - off] : 0;
        __syncthreads();
        buf[tid] += t;
        __syncthreads();
    }
    if (i < NN) excl[i] = buf[tid] - v;
    if (tid == 255) bsums[blockIdx.x] = buf[255];
}

__global__ void k_scan2(const int* __restrict__ bsums, int* __restrict__ boff) {
    __shared__ int buf[512];
    int tid = threadIdx.x;
    int v = (tid < NBLK) ? bsums[tid] : 0;
    buf[tid] = v;
    __syncthreads();
    for (int off = 1; off < 512; off <<= 1) {
        int t = (tid >= off) ? buf[tid - off] : 0;
        __syncthreads();
        buf[tid] += t;
        __syncthreads();
    }
    if (tid < NBLK) boff[tid] = buf[tid] - v;
}

__global__ void k_scan3(int* __restrict__ row_start, const int* __restrict__ boff,
                        int* __restrict__ cursor) {
    int tid = threadIdx.x;
    int i = blockIdx.x * 256 + tid;
    if (i < NN) {
        int r = row_start[i] + boff[blockIdx.x];
        row_start[i] = r;
        cursor[i] = r;
    }
    if (blockIdx.x == 0 && tid == 0) row_start[NN] = EE;
}

__global__ void k_fill(const int* __restrict__ src, const int* __restrict__ dst,
                       int* __restrict__ cursor, int* __restrict__ csr) {
    int e = blockIdx.x * blockDim.x + threadIdx.x;
    if (e < EE) {
        int d = dst[e];
        int p = atomicAdd(&cursor[d], 1);
        csr[p] = src[e];
    }
}

// ---------------- bf16 snapshot of layer input (for the gather) ----------------

__global__ void k_cvt(const float* __restrict__ in, unsigned short* __restrict__ out) {
    int idx = blockIdx.x * 256 + threadIdx.x;   // 1.6M threads, 4 elems each
    const float4 v = *(const float4*)&in[(size_t)idx * 4];
    ushort4 o;
    o.x = f2bf(v.x); o.y = f2bf(v.y); o.z = f2bf(v.z); o.w = f2bf(v.w);
    *(ushort4*)&out[(size_t)idx * 4] = o;
}

// ---------------- GIN stage 1: agg + MLP1 + BN partial stats ----------------
// round-4 structure; neighbor rows gathered as bf16 (128B/row), self term fp32.

__global__ __launch_bounds__(256, 6) void k_agg_mlp1(
    const float* __restrict__ xin, const unsigned short* __restrict__ xb,
    const int* __restrict__ row_start, const int* __restrict__ csr,
    const float* __restrict__ W1, const float* __restrict__ b1,
    float* __restrict__ h_out, float* __restrict__ stats) {
    __shared__ float sW[4096];
    __shared__ float sSum[4][64];
    __shared__ float sSq[4][64];
    int tid = threadIdx.x;
    for (int k = tid; k < 4096; k += 256) sW[k] = W1[k];
    __syncthreads();
    int wave = tid >> 6, lane = tid & 63;
    float bias = b1[lane];
    int base = blockIdx.x * TILE + wave * ROWS;
    float aS = 0.f, aQ = 0.f;
    for (int r = 0; r < ROWS; r++) {
        int i = base + r;
        if (i >= NN) break;
        float s = xin[(size_t)i * 64 + lane];       // self term, fp32
        int e0 = row_start[i], e1 = row_start[i + 1];
        int eb = e0;
        while (eb < e1) {
            int m = e1 - eb; if (m > 64) m = 64;
            int id = (lane < m) ? csr[eb + lane] : 0;
            int k = 0;
            for (; k + 8 <= m; k += 8) {
                // 8 independent 128B row loads in flight before dependent adds
                unsigned short u0 = xb[(unsigned)__shfl(id, k + 0, 64) * 64u + lane];
                unsigned short u1 = xb[(unsigned)__shfl(id, k + 1, 64) * 64u + lane];
                unsigned short u2 = xb[(unsigned)__shfl(id, k + 2, 64) * 64u + lane];
                unsigned short u3 = xb[(unsigned)__shfl(id, k + 3, 64) * 64u + lane];
                unsigned short u4 = xb[(unsigned)__shfl(id, k + 4, 64) * 64u + lane];
                unsigned short u5 = xb[(unsigned)__shfl(id, k + 5, 64) * 64u + lane];
                unsigned short u6 = xb[(unsigned)__shfl(id, k + 6, 64) * 64u + lane];
                unsigned short u7 = xb[(unsigned)__shfl(id, k + 7, 64) * 64u + lane];
                s += ((bf2f(u0) + bf2f(u1)) + (bf2f(u2) + bf2f(u3))) +
                     ((bf2f(u4) + bf2f(u5)) + (bf2f(u6) + bf2f(u7)));
            }
            for (; k + 2 <= m; k += 2) {
                unsigned short u0 = xb[(unsigned)__shfl(id, k + 0, 64) * 64u + lane];
                unsigned short u1 = xb[(unsigned)__shfl(id, k + 1, 64) * 64u + lane];
                s += bf2f(u0) + bf2f(u1);
            }
            for (; k < m; k++)
                s += bf2f(xb[(unsigned)__shfl(id, k, 64) * 64u + lane]);
            eb += m;
        }
        float h0 = bias, h1 = 0.f, h2 = 0.f, h3 = 0.f;
#pragma unroll
        for (int c = 0; c < 64; c += 4) {
            h0 = fmaf(__shfl(s, c + 0, 64), sW[(c + 0) * 64 + lane], h0);
            h1 = fmaf(__shfl(s, c + 1, 64), sW[(c + 1) * 64 + lane], h1);
            h2 = fmaf(__shfl(s, c + 2, 64), sW[(c + 2) * 64 + lane], h2);
            h3 = fmaf(__shfl(s, c + 3, 64), sW[(c + 3) * 64 + lane], h3);
        }
        float h = (h0 + h1) + (h2 + h3);
        h_out[(size_t)i * 64 + lane] = h;
        aS += h;
        aQ += h * h;
    }
    sSum[wave][lane] = aS;
    sSq[wave][lane] = aQ;
    __syncthreads();
    if (wave == 0) {
        float s4 = sSum[0][lane] + sSum[1][lane] + sSum[2][lane] + sSum[3][lane];
        float q4 = sSq[0][lane] + sSq[1][lane] + sSq[2][lane] + sSq[3][lane];
        atomicAdd(&stats[lane], s4);
        atomicAdd(&stats[64 + lane], q4);
    }
}

// ---------------- GIN stage 2: BN + tanh + MLP2 + tanh (+ pool / bf16 copy) ----------------

__global__ __launch_bounds__(256, 6) void k_bn_mlp2(
    const float* __restrict__ h_in, const float* __restrict__ W2,
    const float* __restrict__ b2, const float* __restrict__ gamma,
    const float* __restrict__ beta, const float* __restrict__ stats,
    float* __restrict__ x_out, unsigned short* __restrict__ xb_out,
    float* __restrict__ g_pool, const int* __restrict__ batch) {
    __shared__ float sW[4096];
    int tid = threadIdx.x;
    for (int k = tid; k < 4096; k += 256) sW[k] = W2[k];
    __syncthreads();
    int wave = tid >> 6, lane = tid & 63;
    float bias = b2[lane];
    float mu = stats[lane] * (1.0f / NN);
    float var = stats[64 + lane] * (1.0f / NN) - mu * mu;
    float scale = rsqrtf(var + 1e-5f) * gamma[lane];
    float shift = beta[lane] - mu * scale;
    int base = blockIdx.x * TILE + wave * ROWS;
    float pacc = 0.f;
    int pbid = -1;
    for (int r = 0; r < ROWS; r++) {
        int i = base + r;
        if (i >= NN) break;
        float v = h_in[(size_t)i * 64 + lane];
        float s = fast_tanh(fmaf(v, scale, shift));
        float h0 = bias, h1 = 0.f, h2 = 0.f, h3 = 0.f;
#pragma unroll
        for (int c = 0; c < 64; c += 4) {
            h0 = fmaf(__shfl(s, c + 0, 64), sW[(c + 0) * 64 + lane], h0);
            h1 = fmaf(__shfl(s, c + 1, 64), sW[(c + 1) * 64 + lane], h1);
            h2 = fmaf(__shfl(s, c + 2, 64), sW[(c + 2) * 64 + lane], h2);
            h3 = fmaf(__shfl(s, c + 3, 64), sW[(c + 3) * 64 + lane], h3);
        }
        float o = fast_tanh((h0 + h1) + (h2 + h3));
        if (x_out) {
            x_out[(size_t)i * 64 + lane] = o;
            xb_out[(size_t)i * 64 + lane] = f2bf(o);
        } else {
            int bid = batch[i];  // sorted -> few distinct per wave
            if (bid != pbid) {
                if (pbid >= 0) atomicAdd(&g_pool[pbid * 64 + lane], pacc);
                pacc = 0.f;
                pbid = bid;
            }
            pacc += o;
        }
    }
    if (g_pool && pbid >= 0) atomicAdd(&g_pool[pbid * 64 + lane], pacc);
}

// ---------------- tail ----------------

__global__ void k_pool_proj(const float* __restrict__ g_all, const float* __restrict__ Wg,
                            const float* __restrict__ bg, float* __restrict__ seq) {
    int idx = blockIdx.x * 256 + threadIdx.x;  // S*B*64
    int o = idx & 63, row = idx >> 6;
    float acc = bg[o];
    const float* g = g_all + (size_t)row * 64;
#pragma unroll 8
    for (int c = 0; c < 64; c++) acc = fmaf(g[c], Wg[c * 64 + o], acc);
    seq[idx] = acc;
}

__global__ void k_transpose(const float* __restrict__ in, float* __restrict__ out,
                            int rows, int cols) {
    int idx = blockIdx.x * blockDim.x + threadIdx.x;
    if (idx < rows * cols) {
        int r = idx / cols, c = idx % cols;
        out[c * rows + r] = in[idx];
    }
}

// one block per batch row; loops all 8 timesteps + final sigmoid readout
__global__ __launch_bounds__(128) void k_rnn_all(
    const float* __restrict__ seq, const float* __restrict__ WihT,
    const float* __restrict__ WhhT, const float* __restrict__ bih,
    const float* __restrict__ bhh, const float* __restrict__ Wr,
    const float* __restrict__ br, float* __restrict__ out) {
    int b = blockIdx.x, j = threadIdx.x;
    __shared__ float sh[128];
    __shared__ float sx[64];
    __shared__ float sp[128];
    sh[j] = 0.f;
    float bsum = bih[j] + bhh[j];
    __syncthreads();
    for (int t = 0; t < SQ; t++) {
        if (j < 64) sx[j] = seq[((size_t)t * BB + b) * 64 + j];
        __syncthreads();
        float acc = bsum;
#pragma unroll 16
        for (int c = 0; c < 64; c++) acc = fmaf(sx[c], WihT[c * 128 + j], acc);
#pragma unroll 16
        for (int k = 0; k < 128; k++) acc = fmaf(sh[k], WhhT[k * 128 + j], acc);
        acc = tanhf(acc);
        __syncthreads();
        sh[j] = acc;
        __syncthreads();
    }
    sp[j] = sh[j] * Wr[j];
    __syncthreads();
    if (j == 0) {
        float a = br[0];
        for (int k = 0; k < 128; k++) a += sp[k];
        out[b] = 1.f / (1.f + expf(-a));
    }
}

// ---------------- launch ----------------

extern "C" void kernel_launch(void* const* d_in, const int* in_sizes, int n_in,
                              void* d_out, int out_size, void* d_ws, size_t ws_size,
                              hipStream_t stream) {
    const float* xs    = (const float*)d_in[0];
    const int*   edge  = (const int*)d_in[1];
    const int*   batch = (const int*)d_in[2];
    const float* W1    = (const float*)d_in[3];
    const float* b1    = (const float*)d_in[4];
    const float* gamma = (const float*)d_in[5];
    const float* beta  = (const float*)d_in[6];
    const float* W2    = (const float*)d_in[7];
    const float* b2    = (const float*)d_in[8];
    const float* Wg    = (const float*)d_in[9];
    const float* bg    = (const float*)d_in[10];
    const float* Wih   = (const float*)d_in[11];
    const float* Whh   = (const float*)d_in[12];
    const float* bih   = (const float*)d_in[13];
    const float* bhh   = (const float*)d_in[14];
    const float* Wr    = (const float*)d_in[15];
    const float* br    = (const float*)d_in[16];

    char* p = (char*)d_ws;
    auto alloc = [&](size_t bytes) -> char* {
        char* r = p;
        p += (bytes + 255) & ~(size_t)255;
        return r;
    };
    float*          x_cur     = (float*)alloc((size_t)NN * 64 * 4);
    float*          h_tmp     = (float*)alloc((size_t)NN * 64 * 4);
    unsigned short* x_bf      = (unsigned short*)alloc((size_t)NN * 64 * 2);
    float*          g_all     = (float*)alloc((size_t)SQ * BB * 64 * 4);
    float*          seq       = (float*)alloc((size_t)SQ * BB * 64 * 4);
    float*          WihT      = (float*)alloc((size_t)64 * HRR * 4);
    float*          WhhT      = (float*)alloc((size_t)HRR * HRR * 4);
    float*          stats     = (float*)alloc((size_t)SQ * LL * 128 * 4);
    int*            row_start = (int*)alloc((size_t)(NN + 1) * 4);
    int*            cursor    = (int*)alloc((size_t)NN * 4);
    int*            deg       = (int*)alloc((size_t)NN * 4);
    int*            csr       = (int*)alloc((size_t)EE * 4);
    int*            bsums     = (int*)alloc(512 * 4);
    int*            boff      = (int*)alloc(512 * 4);

    hipMemsetAsync(stats, 0, (size_t)SQ * LL * 128 * 4, stream);
    hipMemsetAsync(g_all, 0, (size_t)SQ * BB * 64 * 4, stream);
    k_transpose<<<(128 * 64 + 255) / 256, 256, 0, stream>>>(Wih, WihT, 128, 64);
    k_transpose<<<(128 * 128 + 255) / 256, 256, 0, stream>>>(Whh, WhhT, 128, 128);

    int ghist = EE / 256;  // 6250
    for (int t = 0; t < SQ; t++) {
        const int* src = edge + (size_t)t * 2 * EE;
        const int* dst = src + EE;
        hipMemsetAsync(deg, 0, (size_t)NN * 4, stream);
        k_hist<<<ghist, 256, 0, stream>>>(dst, deg);
        k_scan1<<<NBLK, 256, 0, stream>>>(deg, row_start, bsums);
        k_scan2<<<1, 512, 0, stream>>>(bsums, boff);
        k_scan3<<<NBLK, 256, 0, stream>>>(row_start, boff, cursor);
        k_fill<<<ghist, 256, 0, stream>>>(src, dst, cursor, csr);
        k_cvt<<<NN * 64 / 1024, 256, 0, stream>>>(xs + (size_t)t * NN * 64, x_bf);
        for (int l = 0; l < LL; l++) {
            int pl = t * LL + l;
            const float* xin = (l == 0) ? xs + (size_t)t * NN * 64 : x_cur;
            k_agg_mlp1<<<NTILE, 256, 0, stream>>>(xin, x_bf, row_start, csr,
                                                  W1 + (size_t)pl * 4096, b1 + (size_t)pl * 64,
                                                  h_tmp, stats + (size_t)pl * 128);
            k_bn_mlp2<<<NTILE, 256, 0, stream>>>(h_tmp, W2 + (size_t)pl * 4096,
                                                 b2 + (size_t)pl * 64, gamma + (size_t)pl * 64,
                                                 beta + (size_t)pl * 64, stats + (size_t)pl * 128,
                                                 (l < 2) ? x_cur : nullptr,
                                                 x_bf,
                                                 (l == 2) ? (g_all + (size_t)t * BB * 64) : nullptr,
                                                 batch);
        }
    }
    k_pool_proj<<<SQ * BB * 64 / 256, 256, 0, stream>>>(g_all, Wg, bg, seq);
    k_rnn_all<<<BB, 128, 0, stream>>>(seq, WihT, WhhT, bih, bhh, Wr, br, (float*)d_out);
}